// Round 1
// 407.632 us; speedup vs baseline: 1.0021x; 1.0021x over previous
//
#include <hip/hip_runtime.h>
#include <math.h>

// Problem constants
#define B_ 32
#define C_ 512
#define G_ 32
#define N_ 1024          // H*W
#define OC3_ 1536        // 3*C
#define EPS_ 1e-5f

typedef __attribute__((ext_vector_type(8))) short short8;
typedef __attribute__((ext_vector_type(4))) float f32x4;

// fp32 -> bf16 RNE
__device__ inline unsigned short f2bf(float f) {
    unsigned u = __builtin_bit_cast(unsigned, f);
    u += 0x7fffu + ((u >> 16) & 1u);
    return (unsigned short)(u >> 16);
}
__device__ inline unsigned pack2(float lo, float hi) {
    return (unsigned)f2bf(lo) | ((unsigned)f2bf(hi) << 16);
}
__device__ inline float bf2f(unsigned short u) {
    return __builtin_bit_cast(float, ((unsigned)u) << 16);
}

// async global->LDS 16 B per lane (gfx950). LDS dest = wave-uniform base +
// lane*16; all call sites use &lds[tid*8] (shorts). Row stride stays an
// unpadded 32 shorts; frag-read bank conflicts handled by XOR chunk swizzle.
typedef const __attribute__((address_space(1))) unsigned int* gas_u32;
typedef __attribute__((address_space(3))) unsigned int* las_u32;
__device__ __forceinline__ void cp16(unsigned short* lds, const unsigned short* g) {
    __builtin_amdgcn_global_load_lds((gas_u32)g, (las_u32)lds, 16, 0, 0);
}

// ---------------------------------------------------------------------------
// GroupNorm statistics. One block per (b,g): 16 ch x 1024 = 16384 floats.
// ---------------------------------------------------------------------------
__global__ __launch_bounds__(256) void gn_stats_kernel(
    const float* __restrict__ x, float* __restrict__ stats)
{
    int bg = blockIdx.x;
    const float4* xv = (const float4*)(x + (size_t)bg * 16 * N_);
    float s = 0.f, ss = 0.f;
    for (int i = threadIdx.x; i < 4096; i += 256) {
        float4 v = xv[i];
        s  += v.x + v.y + v.z + v.w;
        ss += v.x*v.x + v.y*v.y + v.z*v.z + v.w*v.w;
    }
    __shared__ float r1[256], r2[256];
    r1[threadIdx.x] = s; r2[threadIdx.x] = ss;
    __syncthreads();
    for (int off = 128; off > 0; off >>= 1) {
        if (threadIdx.x < off) {
            r1[threadIdx.x] += r1[threadIdx.x + off];
            r2[threadIdx.x] += r2[threadIdx.x + off];
        }
        __syncthreads();
    }
    if (threadIdx.x == 0) {
        float mean = r1[0] * (1.f / 16384.f);
        float var  = r2[0] * (1.f / 16384.f) - mean * mean;
        stats[bg * 2 + 0] = mean;
        stats[bg * 2 + 1] = rsqrtf(var + EPS_);
    }
}

// ---------------------------------------------------------------------------
// fp32 -> bf16 elementwise convert (weights; once per launch).
// ---------------------------------------------------------------------------
__global__ __launch_bounds__(256) void cvt_bf16_kernel(
    const float* __restrict__ src, unsigned short* __restrict__ dst, int n4)
{
    int i = blockIdx.x * 256 + threadIdx.x;
    if (i >= n4) return;
    float4 v = ((const float4*)src)[i];
    uint2 o; o.x = pack2(v.x, v.y); o.y = pack2(v.z, v.w);
    ((uint2*)dst)[i] = o;
}

// ---------------------------------------------------------------------------
// hhatT producer: x[b][c][n] fp32 (coalesced reads) -> GN affine ->
// hhatT[bz][n][c] bf16 via 64x64 LDS tile transpose.
// ---------------------------------------------------------------------------
__global__ __launch_bounds__(256) void hhatT_kernel(
    const float* __restrict__ x, const float* __restrict__ stats,
    const float* __restrict__ nw, const float* __restrict__ nbias,
    unsigned short* __restrict__ hhatT, long sH, int b0)
{
    int bz = blockIdx.z, b = b0 + bz;
    int nt = blockIdx.x * 64, ct = blockIdx.y * 64;
    const float* xb = x + (size_t)b * C_ * N_;
    const float* st = stats + b * 2 * G_;

    __shared__ float T[64][65];
    int tid = threadIdx.x;

    #pragma unroll
    for (int p = 0; p < 4; ++p) {
        int c = p * 16 + (tid >> 4);
        int n4 = (tid & 15) * 4;
        float4 v = *(const float4*)&xb[(size_t)(ct + c) * N_ + nt + n4];
        int g = (ct + c) >> 4;
        float w0 = nw[ct + c] * st[g * 2 + 1];
        float bb = nbias[ct + c] - st[g * 2] * w0;
        T[c][n4]   = v.x * w0 + bb;
        T[c][n4+1] = v.y * w0 + bb;
        T[c][n4+2] = v.z * w0 + bb;
        T[c][n4+3] = v.w * w0 + bb;
    }
    __syncthreads();
    #pragma unroll
    for (int p = 0; p < 2; ++p) {
        int n  = p * 32 + (tid >> 3);
        int c8 = (tid & 7) * 8;
        short8 s;
        #pragma unroll
        for (int u = 0; u < 8; ++u) s[u] = (short)f2bf(T[c8 + u][n]);
        *(short8*)&hhatT[(size_t)bz * sH + (size_t)(nt + n) * C_ + ct + c8] = s;
    }
}

// ---------------------------------------------------------------------------
// 128x128 GEMM: D[row][col] = sum_k A[row][k] * B[col][k]  (+ epilogue)
// BK=32, 4 waves (2x2 of 64x64).
//
// R10: 3-buffer ring, 2-tile-deep prefetch, COUNTED vmcnt (T3+T4).
// Old structure __syncthreads() lowered to s_waitcnt vmcnt(0) every K-step:
// the whole DMA queue drained each iteration, exposing ~900-cyc HBM compulsory
// -miss latency against a ~300-cyc body (counters: MfmaUtil 9.6%, HBM 24%,
// conflicts 0 -> latency-bound). Now: per wave, s_waitcnt vmcnt(4) retires
// only tile-t's 4 DMAs; raw s_barrier publishes the tile across waves; the
// NEWEST tile's loads stay in flight across the barrier. Buffer-overwrite
// safety: stage(t+2) -> buf[(t-1)%3] is issued after the barrier, and every
// wave's reads of tile t-1 complete (lgkm-waited before its MFMAs) before it
// reaches that barrier. sched_barrier(0) pins ds_reads below s_barrier
// (rule #18). LDS 48 KB -> still 3 blocks/CU (VGPR=144 binds at 3 waves/SIMD).
//
// XCD-LOCALITY SWIZZLE (R9): 1-D grid; when nbz%8==0, block ids are laid out
// so bid%8 == batch%8 -- with the hardware's round-robin bid->XCD mapping,
// each batch's blocks stay on ONE XCD's 4 MB L2.
// EPI: 0 bf16 +bias[col] | 1 bf16 +bias[row] | 2 bf16 *scale | 3 bf16
//      4 fp32 +bias[row]+aux (residual)
// ---------------------------------------------------------------------------
template<int EPI>
__global__ __launch_bounds__(256) void gemm128(
    const unsigned short* __restrict__ A, long sA, int lda,
    const unsigned short* __restrict__ B, long sB, int ldb,
    void* __restrict__ Dv, long sD, int ldd,
    const float* __restrict__ bias,
    const float* __restrict__ aux, long sAux,
    int K, float scale, int gx, int gy, int nbz)
{
    int bid = blockIdx.x;
    int nbpb = gx * gy;
    int bx, by, bz;
    if ((nbz & 7) == 0) {
        int xcd = bid & 7;
        int rest = bid >> 3;
        int local = rest % nbpb;
        int bg = rest / nbpb;
        bz = bg * 8 + xcd;
        bx = local % gx;
        by = local / gx;
    } else {
        bz = bid / nbpb;
        int local = bid % nbpb;
        bx = local % gx;
        by = local / gx;
    }

    const unsigned short* Ab = A + (size_t)bz * sA + (size_t)bx * 128 * lda;
    const unsigned short* Bb = B + (size_t)bz * sB + (size_t)by * 128 * ldb;

    __shared__ __align__(16) unsigned short As[3][128 * 32];
    __shared__ __align__(16) unsigned short Bs[3][128 * 32];

    int tid = threadIdx.x;
    int w = tid >> 6, lane = tid & 63;
    int lm = lane & 15, q = lane >> 4;
    int wrow = (w >> 1) * 64, wcol = (w & 1) * 64;

    f32x4 acc[4][4];
    #pragma unroll
    for (int i = 0; i < 4; ++i)
        #pragma unroll
        for (int j = 0; j < 4; ++j) acc[i][j] = (f32x4)(0.f);

    int srow = tid >> 2;                              // staging row (0..63)
    int skc  = (((tid & 3) ^ ((tid >> 3) & 3))) * 8;  // swizzled global chunk
    int fco  = (q ^ ((lm >> 1) & 3)) * 8;             // frag physical chunk

    const unsigned short* a0p = Ab + (size_t)srow        * lda + skc;
    const unsigned short* a1p = Ab + (size_t)(64 + srow) * lda + skc;
    const unsigned short* b0p = Bb + (size_t)srow        * ldb + skc;
    const unsigned short* b1p = Bb + (size_t)(64 + srow) * ldb + skc;

    // prologue: stage tile 0 -> buf 0, tile 1 -> buf 1 (8 DMA/wave in flight)
    cp16(&As[0][tid * 8],        a0p);
    cp16(&As[0][2048 + tid * 8], a1p);
    cp16(&Bs[0][tid * 8],        b0p);
    cp16(&Bs[0][2048 + tid * 8], b1p);
    cp16(&As[1][tid * 8],        a0p + 32);
    cp16(&As[1][2048 + tid * 8], a1p + 32);
    cp16(&Bs[1][tid * 8],        b0p + 32);
    cp16(&Bs[1][2048 + tid * 8], b1p + 32);

    int nIter = K >> 5;     // K/32, >= 16 for all call sites
    int cur = 0;            // buffer holding tile `it` (== it % 3)
    for (int it = 0; it < nIter; ++it) {
        // Retire MY 4 DMAs of tile `it`; keep tile it+1's 4 in flight.
        // (Last iteration: only 4 outstanding, so vmcnt(4) would be a no-op
        //  -> must drain to 0 there.)
        if (it + 1 < nIter) {
            asm volatile("s_waitcnt vmcnt(4)" ::: "memory");
        } else {
            asm volatile("s_waitcnt vmcnt(0)" ::: "memory");
        }
        __builtin_amdgcn_s_barrier();          // tile `it` now whole-block ready
        __builtin_amdgcn_sched_barrier(0);     // pin: no ds_read hoists above

        if (it + 2 < nIter) {
            int nb = cur - 1; if (nb < 0) nb = 2;   // (it+2) % 3
            int off = (it + 2) * 32;
            cp16(&As[nb][tid * 8],        a0p + off);
            cp16(&As[nb][2048 + tid * 8], a1p + off);
            cp16(&Bs[nb][tid * 8],        b0p + off);
            cp16(&Bs[nb][2048 + tid * 8], b1p + off);
        }

        short8 af[4], bf[4];
        #pragma unroll
        for (int i = 0; i < 4; ++i)
            af[i] = *(const short8*)&As[cur][(wrow + i * 16 + lm) * 32 + fco];
        #pragma unroll
        for (int j = 0; j < 4; ++j)
            bf[j] = *(const short8*)&Bs[cur][(wcol + j * 16 + lm) * 32 + fco];
        #pragma unroll
        for (int i = 0; i < 4; ++i)
            #pragma unroll
            for (int j = 0; j < 4; ++j)
                acc[i][j] = __builtin_amdgcn_mfma_f32_16x16x32_bf16(
                    af[i], bf[j], acc[i][j], 0, 0, 0);

        cur = (cur == 2) ? 0 : cur + 1;
    }

    int grow = bx * 128 + wrow;
    int gcol = by * 128 + wcol;

    #pragma unroll
    for (int j = 0; j < 4; ++j) {
        int col = gcol + j * 16 + lm;
        float cb = (EPI == 0) ? bias[col] : 0.f;
        #pragma unroll
        for (int i = 0; i < 4; ++i) {
            #pragma unroll
            for (int r = 0; r < 4; ++r) {
                int row = grow + i * 16 + q * 4 + r;
                float vle = acc[i][j][r];
                if constexpr (EPI == 0) {
                    vle += cb;
                    ((unsigned short*)Dv)[(size_t)bz * sD + (size_t)row * ldd + col] = f2bf(vle);
                } else if constexpr (EPI == 1) {
                    vle += bias[row];
                    ((unsigned short*)Dv)[(size_t)bz * sD + (size_t)row * ldd + col] = f2bf(vle);
                } else if constexpr (EPI == 2) {
                    ((unsigned short*)Dv)[(size_t)bz * sD + (size_t)row * ldd + col] = f2bf(vle * scale);
                } else if constexpr (EPI == 3) {
                    ((unsigned short*)Dv)[(size_t)bz * sD + (size_t)row * ldd + col] = f2bf(vle);
                } else {
                    vle += bias[row] + aux[(size_t)bz * sAux + (size_t)row * ldd + col];
                    ((float*)Dv)[(size_t)bz * sD + (size_t)row * ldd + col] = vle;
                }
            }
        }
    }
}

// ---------------------------------------------------------------------------
// Softmax: in-place on bf16 scores. One WAVE per row (16 elems/lane),
// shuffle reductions, no barriers. Block = 4 waves = 4 rows.
// ---------------------------------------------------------------------------
__global__ __launch_bounds__(256) void softmax_kernel(
    unsigned short* __restrict__ sc, long sSc)
{
    int bz = blockIdx.y;
    int row = blockIdx.x * 4 + (threadIdx.x >> 6);
    int lane = threadIdx.x & 63;
    unsigned short* p = sc + (size_t)bz * sSc + (size_t)row * N_ + lane * 16;

    short8 s0 = *(const short8*)p;
    short8 s1 = *(const short8*)(p + 8);
    float v[16];
    #pragma unroll
    for (int i = 0; i < 8; ++i) {
        v[i]     = bf2f((unsigned short)s0[i]);
        v[8 + i] = bf2f((unsigned short)s1[i]);
    }
    float m = v[0];
    #pragma unroll
    for (int i = 1; i < 16; ++i) m = fmaxf(m, v[i]);
    #pragma unroll
    for (int off = 32; off > 0; off >>= 1) m = fmaxf(m, __shfl_xor(m, off, 64));

    float sum = 0.f;
    #pragma unroll
    for (int i = 0; i < 16; ++i) { v[i] = __expf(v[i] - m); sum += v[i]; }
    #pragma unroll
    for (int off = 32; off > 0; off >>= 1) sum += __shfl_xor(sum, off, 64);
    float inv = 1.f / sum;

    short8 o0, o1;
    #pragma unroll
    for (int i = 0; i < 8; ++i) {
        o0[i] = (short)f2bf(v[i] * inv);
        o1[i] = (short)f2bf(v[8 + i] * inv);
    }
    *(short8*)p = o0;
    *(short8*)(p + 8) = o1;
}

// ---------------------------------------------------------------------------
extern "C" void kernel_launch(void* const* d_in, const int* in_sizes, int n_in,
                              void* d_out, int out_size, void* d_ws, size_t ws_size,
                              hipStream_t stream) {
    const float* x      = (const float*)d_in[0];
    const float* norm_w = (const float*)d_in[1];
    const float* norm_b = (const float*)d_in[2];
    const float* qkv_w  = (const float*)d_in[3];
    const float* qkv_b  = (const float*)d_in[4];
    const float* proj_w = (const float*)d_in[5];
    const float* proj_b = (const float*)d_in[6];
    float* out = (float*)d_out;

    // Fixed region: stats (8 KB) + bf16 weights (2 MB).
    char* ws = (char*)d_ws;
    float* stats = (float*)ws;
    unsigned short* wqkv  = (unsigned short*)(ws + 8192);   // 1536x512
    unsigned short* wproj = wqkv + (size_t)OC3_ * C_;       // 512x512
    char* base = (char*)(wproj + (size_t)C_ * C_);
    const size_t fixed = 8192 + (size_t)OC3_ * C_ * 2 + (size_t)C_ * C_ * 2;

    // Per-batch aliased region: 6 MB.
    //   [0,2M)  qkT bf16 [n][1024]
    //   [2,3M)  v bf16 [c][n]
    //   [3,4M)  hhatT bf16 [n][c]  -> after GEMM2 reused as houtT bf16 [n][c]
    //   [4,6M)  sc bf16 [n][m]     -> softmax in-place -> attn
    const size_t REG = 6u << 20;
    const long RSH = (long)(REG / 2);         // region stride in shorts

    size_t avail = ws_size > fixed ? ws_size - fixed : 0;
    int chunk = (int)(avail / REG);
    if (chunk < 1) chunk = 1;
    if (chunk > B_) chunk = B_;

    gn_stats_kernel<<<dim3(B_ * G_), dim3(256), 0, stream>>>(x, stats);
    cvt_bf16_kernel<<<dim3((OC3_ * C_ / 4 + 255) / 256), dim3(256), 0, stream>>>(
        qkv_w, wqkv, OC3_ * C_ / 4);
    cvt_bf16_kernel<<<dim3((C_ * C_ / 4 + 255) / 256), dim3(256), 0, stream>>>(
        proj_w, wproj, C_ * C_ / 4);

    const float scale = 0.044194173824159216f;  // 512^-0.5

    unsigned short* qkT   = (unsigned short*)base;
    unsigned short* vbuf  = (unsigned short*)(base + (2u << 20));
    unsigned short* hhatT = (unsigned short*)(base + (3u << 20));
    unsigned short* houtT = (unsigned short*)(base + (3u << 20)); // aliases hhatT
    unsigned short* sc    = (unsigned short*)(base + (4u << 20)); // scores/attn

    for (int b0 = 0; b0 < B_; b0 += chunk) {
        int nb = B_ - b0 < chunk ? B_ - b0 : chunk;

        hhatT_kernel<<<dim3(N_/64, C_/64, nb), dim3(256), 0, stream>>>(
            x, stats, norm_w, norm_b, hhatT, RSH, b0);

        // GEMM1a: qkT[n][o] = hhatT[n][:] . Wqk[o][:]   (o in [0,1024))
        gemm128<0><<<dim3(8 * 8 * nb), dim3(256), 0, stream>>>(
            hhatT, RSH, C_,  wqkv, 0, C_,
            qkT, RSH, 1024,  qkv_b, nullptr, 0, C_, 0.f, 8, 8, nb);

        // GEMM1b: v[c][n] = Wv[c][:] . hhatT[n][:]
        gemm128<1><<<dim3(4 * 8 * nb), dim3(256), 0, stream>>>(
            wqkv + (size_t)1024 * C_, 0, C_,  hhatT, RSH, C_,
            vbuf, RSH, N_,  qkv_b + 1024, nullptr, 0, C_, 0.f, 4, 8, nb);

        // GEMM2: sc[n][m] = bf16( scale * qkT[n][0:512] . qkT[m][512:1024] )
        gemm128<2><<<dim3(8 * 8 * nb), dim3(256), 0, stream>>>(
            qkT, RSH, 1024,  qkT + 512, RSH, 1024,
            sc, RSH, N_,  nullptr, nullptr, 0, C_, scale, 8, 8, nb);

        softmax_kernel<<<dim3(N_/4, nb), dim3(256), 0, stream>>>(sc, RSH);

        // GEMM3: houtT[n][c] = attn[n][:] . v[c][:]   (K = 1024)
        gemm128<3><<<dim3(8 * 4 * nb), dim3(256), 0, stream>>>(
            sc, RSH, N_,  vbuf, RSH, N_,
            houtT, RSH, C_,  nullptr, nullptr, 0, N_, 0.f, 8, 4, nb);

        // GEMM4: out[o][n] = pw[o][:] . houtT[n][:] + pb[o] + x[o][n]
        gemm128<4><<<dim3(4 * 8 * nb), dim3(256), 0, stream>>>(
            wproj, 0, C_,  houtT, RSH, C_,
            out + (size_t)b0 * C_ * N_, (long)C_ * N_, N_,
            proj_b, x + (size_t)b0 * C_ * N_, (long)C_ * N_, C_, 0.f, 4, 8, nb);
    }
}